// Round 6
// baseline (2737.506 us; speedup 1.0000x reference)
//
#include <hip/hip_runtime.h>

constexpr int SEQ = 2048;
constexpr int DIM = 1024;
constexpr int BATCH = 4;

// ---------------------------------------------------------------------------
// Plain fp32 NT GEMM: C[m][n] = alpha * sum_k A[m][k] * B[n][k].
// Faithful to the reference: q = x @ WQ^T with W stored [out, in].
// Block 256 = 16x16 threads, tile 64(m) x 64(n) x 16(k), 4x4 microtile.
// causal!=0: skip tiles entirely above the diagonal.
// ---------------------------------------------------------------------------
__global__ __launch_bounds__(256) void gemm_nt_f32(
    const float* __restrict__ A, const float* __restrict__ B,
    float* __restrict__ C, int Kdim, int lda, int ldb, int ldc,
    float alpha, int causal)
{
    const int n0 = blockIdx.x * 64, m0 = blockIdx.y * 64;
    if (causal && n0 > m0 + 63) return;
    __shared__ float As[64][17];
    __shared__ float Bs[64][17];
    const int t = threadIdx.x;
    const int tx = t & 15, ty = t >> 4;
    const int kk0 = t & 15, mm0 = t >> 4;

    float acc[4][4];
#pragma unroll
    for (int i = 0; i < 4; ++i)
#pragma unroll
        for (int j = 0; j < 4; ++j) acc[i][j] = 0.f;

    for (int k0 = 0; k0 < Kdim; k0 += 16) {
        __syncthreads();
#pragma unroll
        for (int p = 0; p < 4; ++p) {
            const int mm = mm0 + p * 16;
            As[mm][kk0] = A[(size_t)(m0 + mm) * lda + k0 + kk0];
            Bs[mm][kk0] = B[(size_t)(n0 + mm) * ldb + k0 + kk0];
        }
        __syncthreads();
#pragma unroll
        for (int kk = 0; kk < 16; ++kk) {
            float a[4], b[4];
#pragma unroll
            for (int i = 0; i < 4; ++i) a[i] = As[ty * 4 + i][kk];
#pragma unroll
            for (int j = 0; j < 4; ++j) b[j] = Bs[tx * 4 + j][kk];
#pragma unroll
            for (int i = 0; i < 4; ++i)
#pragma unroll
                for (int j = 0; j < 4; ++j) acc[i][j] += a[i] * b[j];
        }
    }
#pragma unroll
    for (int i = 0; i < 4; ++i)
#pragma unroll
        for (int j = 0; j < 4; ++j)
            C[(size_t)(m0 + ty * 4 + i) * ldc + n0 + tx * 4 + j] = acc[i][j] * alpha;
}

// ---------------------------------------------------------------------------
// Row-wise masked softmax, fp32 in-place over S (one block per row).
// Faithful: j > i masked; j <= i masked iff S[i][j] == 0. Writes full row.
// ---------------------------------------------------------------------------
__global__ __launch_bounds__(256) void softmax_inplace(
    float* __restrict__ S)
{
    const int i = blockIdx.x, t = threadIdx.x;
    const int wid = t >> 6, lane = t & 63;
    __shared__ float redm[4], reds[4];
    float sv[8];
    float mx = -__builtin_inff();
#pragma unroll
    for (int u = 0; u < 8; ++u) {
        const int j = u * 256 + t;
        float s = -__builtin_inff();
        if (j <= i) {
            float x = S[(size_t)i * SEQ + j];
            s = (x == 0.f) ? -__builtin_inff() : x;
        }
        sv[u] = s;
        mx = fmaxf(mx, s);
    }
#pragma unroll
    for (int off = 1; off < 64; off <<= 1) mx = fmaxf(mx, __shfl_xor(mx, off));
    if (lane == 0) redm[wid] = mx;
    __syncthreads();
    const float M = fmaxf(fmaxf(redm[0], redm[1]), fmaxf(redm[2], redm[3]));
    float sum = 0.f;
#pragma unroll
    for (int u = 0; u < 8; ++u) {
        float e = __expf(sv[u] - M);  // -inf -> 0
        sv[u] = e;
        sum += e;
    }
#pragma unroll
    for (int off = 1; off < 64; off <<= 1) sum += __shfl_xor(sum, off);
    if (lane == 0) reds[wid] = sum;
    __syncthreads();
    const float rinv = 1.f / (reds[0] + reds[1] + reds[2] + reds[3]);
#pragma unroll
    for (int u = 0; u < 8; ++u)
        S[(size_t)i * SEQ + u * 256 + t] = sv[u] * rinv;
}

// ---------------------------------------------------------------------------
// fp32 NN GEMM, fp32 store: Out = P @ V.  A = P [SEQ x SEQ], B = V [SEQ x DIM].
// ---------------------------------------------------------------------------
__global__ __launch_bounds__(256) void gemm_nn_pv(
    const float* __restrict__ A, const float* __restrict__ B,
    float* __restrict__ Out)
{
    const int n0 = blockIdx.x * 64, m0 = blockIdx.y * 64;
    __shared__ float As[64][17];
    __shared__ float Bs[16][65];
    const int t = threadIdx.x;
    const int tx = t & 15, ty = t >> 4;
    const int kk0 = t & 15, mm0 = t >> 4;   // for As
    const int nn0 = t & 63, kr0 = t >> 6;   // for Bs

    float acc[4][4];
#pragma unroll
    for (int i = 0; i < 4; ++i)
#pragma unroll
        for (int j = 0; j < 4; ++j) acc[i][j] = 0.f;

    for (int k0 = 0; k0 < SEQ; k0 += 16) {
        __syncthreads();
#pragma unroll
        for (int p = 0; p < 4; ++p) {
            const int mm = mm0 + p * 16;
            As[mm][kk0] = A[(size_t)(m0 + mm) * SEQ + k0 + kk0];
            const int kk = kr0 + p * 4;
            Bs[kk][nn0] = B[(size_t)(k0 + kk) * DIM + n0 + nn0];
        }
        __syncthreads();
#pragma unroll
        for (int kk = 0; kk < 16; ++kk) {
            float a[4], b[4];
#pragma unroll
            for (int i = 0; i < 4; ++i) a[i] = As[ty * 4 + i][kk];
#pragma unroll
            for (int j = 0; j < 4; ++j) b[j] = Bs[kk][tx * 4 + j];
#pragma unroll
            for (int i = 0; i < 4; ++i)
#pragma unroll
                for (int j = 0; j < 4; ++j) acc[i][j] += a[i] * b[j];
        }
    }
#pragma unroll
    for (int i = 0; i < 4; ++i)
#pragma unroll
        for (int j = 0; j < 4; ++j)
            Out[(size_t)(m0 + ty * 4 + i) * DIM + n0 + tx * 4 + j] = acc[i][j];
}

extern "C" void kernel_launch(void* const* d_in, const int* in_sizes, int n_in,
                              void* d_out, int out_size, void* d_ws, size_t ws_size,
                              hipStream_t stream)
{
    (void)out_size; (void)ws_size;
    // x identified by size (8.4M elements); weights keep their relative order.
    const float* X = nullptr;
    const float* Wv[3] = {nullptr, nullptr, nullptr};
    int nw = 0;
    for (int i = 0; i < n_in; ++i) {
        if (in_sizes[i] == (int)((size_t)BATCH * SEQ * DIM))
            X = (const float*)d_in[i];
        else if (nw < 3)
            Wv[nw++] = (const float*)d_in[i];
    }
    const float* WQ = Wv[0];
    const float* WK = Wv[1];
    const float* WV = Wv[2];

    float* Qf = (float*)d_ws;                       // 8 MB
    float* Kf = Qf + (size_t)SEQ * DIM;             // 8 MB
    float* Vf = Kf + (size_t)SEQ * DIM;             // 8 MB
    float* Sf = Vf + (size_t)SEQ * DIM;             // 16 MB
    float* Out = (float*)d_out;                     // fp32 output (ref is fp32)

    for (int b = 0; b < BATCH; ++b) {
        const float* Xb = X + (size_t)b * SEQ * DIM;
        // Q/K/V = Xb @ W^T  (NT, W stored [out, in] — faithful to reference)
        gemm_nt_f32<<<dim3(DIM / 64, SEQ / 64), 256, 0, stream>>>(
            Xb, WQ, Qf, DIM, DIM, DIM, DIM, 1.0f, 0);
        gemm_nt_f32<<<dim3(DIM / 64, SEQ / 64), 256, 0, stream>>>(
            Xb, WK, Kf, DIM, DIM, DIM, DIM, 1.0f, 0);
        gemm_nt_f32<<<dim3(DIM / 64, SEQ / 64), 256, 0, stream>>>(
            Xb, WV, Vf, DIM, DIM, DIM, DIM, 1.0f, 0);
        // S = Q K^T * SCALE (NT), skipping tiles above the diagonal
        gemm_nt_f32<<<dim3(SEQ / 64, SEQ / 64), 256, 0, stream>>>(
            Qf, Kf, Sf, DIM, DIM, DIM, SEQ, 0.03125f, 1);
        // P = masked softmax(S), in place, full rows (zeros above diagonal)
        softmax_inplace<<<dim3(SEQ), 256, 0, stream>>>(Sf);
        // out_b = P @ V (NN), fp32 store
        gemm_nn_pv<<<dim3(DIM / 64, SEQ / 64), 256, 0, stream>>>(
            Sf, Vf, Out + (size_t)b * SEQ * DIM);
    }
}

// Round 7
// 527.577 us; speedup vs baseline: 5.1888x; 5.1888x over previous
//
#include <hip/hip_runtime.h>

typedef __bf16 bf16x8 __attribute__((ext_vector_type(8)));
typedef unsigned short u16x8v __attribute__((ext_vector_type(8)));
typedef unsigned short u16x4v __attribute__((ext_vector_type(4)));
typedef float f32x4 __attribute__((ext_vector_type(4)));

constexpr int SEQ = 2048;
constexpr int DIM = 1024;
constexpr int BATCH = 4;
constexpr size_t NBS = (size_t)BATCH * SEQ * DIM;  // 8388608

static __device__ __forceinline__ unsigned short f2bf(float f) {
    unsigned int u = __builtin_bit_cast(unsigned int, f);
    u += 0x7FFFu + ((u >> 16) & 1u);  // RNE
    return (unsigned short)(u >> 16);
}
static __device__ __forceinline__ float bf2f(unsigned short h) {
    return __builtin_bit_cast(float, (unsigned int)h << 16);
}
static __device__ __forceinline__ bf16x8 ldsld(const unsigned short* p) {
    return __builtin_bit_cast(bf16x8, *(const u16x8v*)p);
}

// ---------------------------------------------------------------------------
// fp32 -> bf16 hi + bf16 lo (lo = rne(x - hi)); 4 elems/thread.
// ---------------------------------------------------------------------------
__global__ __launch_bounds__(256) void split_f32(
    const float* __restrict__ in, unsigned short* __restrict__ hi,
    unsigned short* __restrict__ lo, int n4)
{
    int i = blockIdx.x * 256 + threadIdx.x;
    if (i >= n4) return;
    float4 f = ((const float4*)in)[i];
    u16x4v h, l;
    h.x = f2bf(f.x); l.x = f2bf(f.x - bf2f(h.x));
    h.y = f2bf(f.y); l.y = f2bf(f.y - bf2f(h.y));
    h.z = f2bf(f.z); l.z = f2bf(f.z - bf2f(h.z));
    h.w = f2bf(f.w); l.w = f2bf(f.w - bf2f(h.w));
    ((u16x4v*)hi)[i] = h;
    ((u16x4v*)lo)[i] = l;
}

// ---------------------------------------------------------------------------
// QKV GEMM, split-3 MFMA: O = (Xh+Xl)(Wh+Wl)^T via hh+hl+lh (NT, W [out,in]).
// 128x128 tile, 4 waves x 64x64 (4x4 MFMA 16x16x32).
// z=0 -> Qh/Ql, z=1 -> Kh/Kl, z=2 -> Vt (bf16, transposed [b][d][s]).
// ---------------------------------------------------------------------------
__global__ __launch_bounds__(256) void qkv_gemm3(
    const unsigned short* __restrict__ Xh, const unsigned short* __restrict__ Xl,
    const unsigned short* __restrict__ Wh, const unsigned short* __restrict__ Wl,
    unsigned short* __restrict__ Qh, unsigned short* __restrict__ Ql,
    unsigned short* __restrict__ Kh, unsigned short* __restrict__ Kl,
    unsigned short* __restrict__ Vt)
{
    __shared__ unsigned short Ah[128 * 40], Al[128 * 40];
    __shared__ unsigned short Bh[128 * 40], Bl[128 * 40];
    const int m0 = blockIdx.x * 128, n0 = blockIdx.y * 128, z = blockIdx.z;
    const unsigned short* Wzh = Wh + (size_t)z * DIM * DIM;
    const unsigned short* Wzl = Wl + (size_t)z * DIM * DIM;
    const int tid = threadIdx.x;
    const int w = tid >> 6, lane = tid & 63, q = lane >> 4, c = lane & 15;
    const int wrow = (w >> 1) * 64, wcol = (w & 1) * 64;

    f32x4 acc[4][4];
#pragma unroll
    for (int a = 0; a < 4; ++a)
#pragma unroll
        for (int b = 0; b < 4; ++b) acc[a][b] = (f32x4){0.f, 0.f, 0.f, 0.f};

    const int srow = tid >> 1, sh = (tid & 1) * 16;
    for (int k0 = 0; k0 < DIM; k0 += 32) {
        __syncthreads();
        {
            const size_t ga = (size_t)(m0 + srow) * DIM + k0 + sh;
            const size_t gb = (size_t)(n0 + srow) * DIM + k0 + sh;
            unsigned short* sa  = Ah + srow * 40 + sh;
            unsigned short* sal = Al + srow * 40 + sh;
            unsigned short* sb  = Bh + srow * 40 + sh;
            unsigned short* sbl = Bl + srow * 40 + sh;
            *(u16x8v*)sa        = *(const u16x8v*)(Xh + ga);
            *(u16x8v*)(sa + 8)  = *(const u16x8v*)(Xh + ga + 8);
            *(u16x8v*)sal       = *(const u16x8v*)(Xl + ga);
            *(u16x8v*)(sal + 8) = *(const u16x8v*)(Xl + ga + 8);
            *(u16x8v*)sb        = *(const u16x8v*)(Wzh + gb);
            *(u16x8v*)(sb + 8)  = *(const u16x8v*)(Wzh + gb + 8);
            *(u16x8v*)sbl       = *(const u16x8v*)(Wzl + gb);
            *(u16x8v*)(sbl + 8) = *(const u16x8v*)(Wzl + gb + 8);
        }
        __syncthreads();
        bf16x8 ah[4], al[4], bh[4], bl[4];
#pragma unroll
        for (int mi = 0; mi < 4; ++mi) {
            ah[mi] = ldsld(Ah + (wrow + mi * 16 + c) * 40 + q * 8);
            al[mi] = ldsld(Al + (wrow + mi * 16 + c) * 40 + q * 8);
        }
#pragma unroll
        for (int ni = 0; ni < 4; ++ni) {
            bh[ni] = ldsld(Bh + (wcol + ni * 16 + c) * 40 + q * 8);
            bl[ni] = ldsld(Bl + (wcol + ni * 16 + c) * 40 + q * 8);
        }
#pragma unroll
        for (int mi = 0; mi < 4; ++mi)
#pragma unroll
            for (int ni = 0; ni < 4; ++ni) {
                acc[mi][ni] = __builtin_amdgcn_mfma_f32_16x16x32_bf16(al[mi], bh[ni], acc[mi][ni], 0, 0, 0);
                acc[mi][ni] = __builtin_amdgcn_mfma_f32_16x16x32_bf16(ah[mi], bl[ni], acc[mi][ni], 0, 0, 0);
                acc[mi][ni] = __builtin_amdgcn_mfma_f32_16x16x32_bf16(ah[mi], bh[ni], acc[mi][ni], 0, 0, 0);
            }
    }

    if (z < 2) {
        unsigned short* OH = z ? Kh : Qh;
        unsigned short* OL = z ? Kl : Ql;
#pragma unroll
        for (int mi = 0; mi < 4; ++mi)
#pragma unroll
            for (int ni = 0; ni < 4; ++ni) {
                const int col = n0 + wcol + ni * 16 + c;
#pragma unroll
                for (int r = 0; r < 4; ++r) {
                    const int row = m0 + wrow + mi * 16 + q * 4 + r;
                    float a = acc[mi][ni][r];
                    unsigned short h = f2bf(a);
                    OH[(size_t)row * DIM + col] = h;
                    OL[(size_t)row * DIM + col] = f2bf(a - bf2f(h));
                }
            }
    } else {
#pragma unroll
        for (int mi = 0; mi < 4; ++mi) {
            const int mg = m0 + wrow + mi * 16 + q * 4;
            const int bb = mg >> 11, ss = mg & (SEQ - 1);
#pragma unroll
            for (int ni = 0; ni < 4; ++ni) {
                const int col = n0 + wcol + ni * 16 + c;
                u16x4v v;
                v.x = f2bf(acc[mi][ni][0]);
                v.y = f2bf(acc[mi][ni][1]);
                v.z = f2bf(acc[mi][ni][2]);
                v.w = f2bf(acc[mi][ni][3]);
                *(u16x4v*)(Vt + ((size_t)bb * DIM + col) * SEQ + ss) = v;
            }
        }
    }
}

// ---------------------------------------------------------------------------
// Scores GEMM, split-3 MFMA, one batch: S = (Qh+Ql)(Kh+Kl)^T * SCALE, fp32.
// Skips tiles entirely above the diagonal.
// ---------------------------------------------------------------------------
__global__ __launch_bounds__(256) void scores_gemm3(
    const unsigned short* __restrict__ Qh, const unsigned short* __restrict__ Ql,
    const unsigned short* __restrict__ Kh, const unsigned short* __restrict__ Kl,
    float* __restrict__ S)
{
    if (blockIdx.y > blockIdx.x) return;
    __shared__ unsigned short Ah[128 * 40], Al[128 * 40];
    __shared__ unsigned short Bh[128 * 40], Bl[128 * 40];
    const int i0 = blockIdx.x * 128, j0 = blockIdx.y * 128;
    const int tid = threadIdx.x;
    const int w = tid >> 6, lane = tid & 63, q = lane >> 4, c = lane & 15;
    const int wrow = (w >> 1) * 64, wcol = (w & 1) * 64;

    f32x4 acc[4][4];
#pragma unroll
    for (int a = 0; a < 4; ++a)
#pragma unroll
        for (int b = 0; b < 4; ++b) acc[a][b] = (f32x4){0.f, 0.f, 0.f, 0.f};

    const int srow = tid >> 1, sh = (tid & 1) * 16;
    for (int k0 = 0; k0 < DIM; k0 += 32) {
        __syncthreads();
        {
            const size_t ga = (size_t)(i0 + srow) * DIM + k0 + sh;
            const size_t gb = (size_t)(j0 + srow) * DIM + k0 + sh;
            unsigned short* sa  = Ah + srow * 40 + sh;
            unsigned short* sal = Al + srow * 40 + sh;
            unsigned short* sb  = Bh + srow * 40 + sh;
            unsigned short* sbl = Bl + srow * 40 + sh;
            *(u16x8v*)sa        = *(const u16x8v*)(Qh + ga);
            *(u16x8v*)(sa + 8)  = *(const u16x8v*)(Qh + ga + 8);
            *(u16x8v*)sal       = *(const u16x8v*)(Ql + ga);
            *(u16x8v*)(sal + 8) = *(const u16x8v*)(Ql + ga + 8);
            *(u16x8v*)sb        = *(const u16x8v*)(Kh + gb);
            *(u16x8v*)(sb + 8)  = *(const u16x8v*)(Kh + gb + 8);
            *(u16x8v*)sbl       = *(const u16x8v*)(Kl + gb);
            *(u16x8v*)(sbl + 8) = *(const u16x8v*)(Kl + gb + 8);
        }
        __syncthreads();
        bf16x8 ah[4], al[4], bh[4], bl[4];
#pragma unroll
        for (int mi = 0; mi < 4; ++mi) {
            ah[mi] = ldsld(Ah + (wrow + mi * 16 + c) * 40 + q * 8);
            al[mi] = ldsld(Al + (wrow + mi * 16 + c) * 40 + q * 8);
        }
#pragma unroll
        for (int ni = 0; ni < 4; ++ni) {
            bh[ni] = ldsld(Bh + (wcol + ni * 16 + c) * 40 + q * 8);
            bl[ni] = ldsld(Bl + (wcol + ni * 16 + c) * 40 + q * 8);
        }
#pragma unroll
        for (int mi = 0; mi < 4; ++mi)
#pragma unroll
            for (int ni = 0; ni < 4; ++ni) {
                acc[mi][ni] = __builtin_amdgcn_mfma_f32_16x16x32_bf16(al[mi], bh[ni], acc[mi][ni], 0, 0, 0);
                acc[mi][ni] = __builtin_amdgcn_mfma_f32_16x16x32_bf16(ah[mi], bl[ni], acc[mi][ni], 0, 0, 0);
                acc[mi][ni] = __builtin_amdgcn_mfma_f32_16x16x32_bf16(ah[mi], bh[ni], acc[mi][ni], 0, 0, 0);
            }
    }
#pragma unroll
    for (int mi = 0; mi < 4; ++mi)
#pragma unroll
        for (int ni = 0; ni < 4; ++ni) {
            const int col = j0 + wcol + ni * 16 + c;
#pragma unroll
            for (int r = 0; r < 4; ++r) {
                const int row = i0 + wrow + mi * 16 + q * 4 + r;
                S[(size_t)row * SEQ + col] = acc[mi][ni][r] * 0.03125f;
            }
        }
}

// ---------------------------------------------------------------------------
// Row-wise masked softmax: fp32 S -> bf16 P (full rows, masked -> 0).
// Faithful: j > i masked; j <= i masked iff S == 0.
// ---------------------------------------------------------------------------
__global__ __launch_bounds__(256) void softmax_row(
    const float* __restrict__ S, unsigned short* __restrict__ P)
{
    const int i = blockIdx.x, t = threadIdx.x;
    const int wid = t >> 6, lane = t & 63;
    __shared__ float redm[4], reds[4];
    float sv[8];
    float mx = -__builtin_inff();
#pragma unroll
    for (int u = 0; u < 8; ++u) {
        const int j = u * 256 + t;
        float s = -__builtin_inff();
        if (j <= i) {
            float x = S[(size_t)i * SEQ + j];
            s = (x == 0.f) ? -__builtin_inff() : x;
        }
        sv[u] = s;
        mx = fmaxf(mx, s);
    }
#pragma unroll
    for (int off = 1; off < 64; off <<= 1) mx = fmaxf(mx, __shfl_xor(mx, off));
    if (lane == 0) redm[wid] = mx;
    __syncthreads();
    const float M = fmaxf(fmaxf(redm[0], redm[1]), fmaxf(redm[2], redm[3]));
    float sum = 0.f;
#pragma unroll
    for (int u = 0; u < 8; ++u) {
        float e = __expf(sv[u] - M);
        sv[u] = e;
        sum += e;
    }
#pragma unroll
    for (int off = 1; off < 64; off <<= 1) sum += __shfl_xor(sum, off);
    if (lane == 0) reds[wid] = sum;
    __syncthreads();
    const float rinv = 1.f / (reds[0] + reds[1] + reds[2] + reds[3]);
#pragma unroll
    for (int u = 0; u < 8; ++u)
        P[(size_t)i * SEQ + u * 256 + t] = f2bf(sv[u] * rinv);
}

// ---------------------------------------------------------------------------
// out = P @ V via Vt (NT MFMA), fp32 store. Tile 64(i) x 128(d); k-loop
// truncated at causal bound i0+64.
// ---------------------------------------------------------------------------
__global__ __launch_bounds__(256) void pv_gemm(
    const unsigned short* __restrict__ Pm, const unsigned short* __restrict__ Vt,
    float* __restrict__ Out)
{
    __shared__ unsigned short Ps[64 * 40];
    __shared__ unsigned short Vs[128 * 40];
    const int i0 = blockIdx.x * 64, d0 = blockIdx.y * 128, b = blockIdx.z;
    const int tid = threadIdx.x;
    const int w = tid >> 6, lane = tid & 63, q = lane >> 4, c = lane & 15;
    const int wrow = (w >> 1) * 32, wcol = (w & 1) * 64;

    f32x4 acc[2][4];
#pragma unroll
    for (int a = 0; a < 2; ++a)
#pragma unroll
        for (int bq = 0; bq < 4; ++bq) acc[a][bq] = (f32x4){0.f, 0.f, 0.f, 0.f};

    const int njs = i0 / 32 + 2;
    const int prow = tid >> 2, pcol = (tid & 3) * 8;
    const int vrow = tid >> 1, vcol = (tid & 1) * 16;

    for (int ks = 0; ks < njs; ++ks) {
        const int j0 = ks * 32;
        __syncthreads();
        *(u16x8v*)(Ps + prow * 40 + pcol) =
            *(const u16x8v*)(Pm + ((size_t)b * SEQ + i0 + prow) * SEQ + j0 + pcol);
        {
            const unsigned short* g = Vt + ((size_t)b * DIM + d0 + vrow) * SEQ + j0 + vcol;
            unsigned short* sv_ = Vs + vrow * 40 + vcol;
            *(u16x8v*)sv_       = *(const u16x8v*)g;
            *(u16x8v*)(sv_ + 8) = *(const u16x8v*)(g + 8);
        }
        __syncthreads();
        bf16x8 bfr[4];
#pragma unroll
        for (int ni = 0; ni < 4; ++ni)
            bfr[ni] = ldsld(Vs + (wcol + ni * 16 + c) * 40 + q * 8);
#pragma unroll
        for (int mi = 0; mi < 2; ++mi) {
            bf16x8 a = ldsld(Ps + (wrow + mi * 16 + c) * 40 + q * 8);
#pragma unroll
            for (int ni = 0; ni < 4; ++ni)
                acc[mi][ni] = __builtin_amdgcn_mfma_f32_16x16x32_bf16(a, bfr[ni], acc[mi][ni], 0, 0, 0);
        }
    }
#pragma unroll
    for (int mi = 0; mi < 2; ++mi)
#pragma unroll
        for (int ni = 0; ni < 4; ++ni) {
            const int dcol = d0 + wcol + ni * 16 + c;
#pragma unroll
            for (int r = 0; r < 4; ++r) {
                const int i = i0 + wrow + mi * 16 + q * 4 + r;
                Out[((size_t)b * SEQ + i) * DIM + dcol] = acc[mi][ni][r];
            }
        }
}

extern "C" void kernel_launch(void* const* d_in, const int* in_sizes, int n_in,
                              void* d_out, int out_size, void* d_ws, size_t ws_size,
                              hipStream_t stream)
{
    (void)out_size; (void)ws_size;
    const float* X = nullptr;
    const float* Wv[3] = {nullptr, nullptr, nullptr};
    int nw = 0;
    for (int i = 0; i < n_in; ++i) {
        if (in_sizes[i] == (int)NBS)
            X = (const float*)d_in[i];
        else if (nw < 3)
            Wv[nw++] = (const float*)d_in[i];
    }

    unsigned short* ws = (unsigned short*)d_ws;
    unsigned short* Qh = ws;                 // 16 MB each
    unsigned short* Ql = ws + NBS;
    unsigned short* Kh = ws + 2 * NBS;
    unsigned short* Kl = ws + 3 * NBS;
    unsigned short* Vt = ws + 4 * NBS;
    unsigned short* Xh = ws + 5 * NBS;       // consumed by qkv_gemm3
    unsigned short* Xl = ws + 6 * NBS;
    unsigned short* Pp = ws + 5 * NBS;       // P aliases Xh/Xl after qkv (2*NBS)
    unsigned short* Wh = ws + 7 * NBS;       // 6 MB
    unsigned short* Wl = Wh + (size_t)3 * DIM * DIM;  // 6 MB
    float* Sf = (float*)(ws + 7 * NBS);      // S aliases Wh/Wl after qkv (16 MB)
    float* Out = (float*)d_out;

    split_f32<<<dim3((int)(NBS / 4 / 256)), 256, 0, stream>>>(X, Xh, Xl, (int)(NBS / 4));
    const int wn4 = DIM * DIM / 4;
    for (int z = 0; z < 3; ++z)
        split_f32<<<dim3(wn4 / 256), 256, 0, stream>>>(
            Wv[z], Wh + (size_t)z * DIM * DIM, Wl + (size_t)z * DIM * DIM, wn4);

    qkv_gemm3<<<dim3(64, 8, 3), 256, 0, stream>>>(Xh, Xl, Wh, Wl, Qh, Ql, Kh, Kl, Vt);

    for (int b = 0; b < BATCH; ++b) {
        const size_t bo = (size_t)b * SEQ * DIM;
        scores_gemm3<<<dim3(16, 16), 256, 0, stream>>>(Qh + bo, Ql + bo, Kh + bo, Kl + bo, Sf);
        softmax_row<<<dim3(SEQ), 256, 0, stream>>>(Sf, Pp + (size_t)b * SEQ * SEQ);
    }

    pv_gemm<<<dim3(32, 8, 4), 256, 0, stream>>>(Pp, Vt, Out);
}